// Round 11
// baseline (452.678 us; speedup 1.0000x reference)
//
#include <hip/hip_runtime.h>
#include <hip/hip_bf16.h>
#include <math.h>

#define N_NODES 100000
#define N_EDGES 1600000
#define HC 64          // H*C
#define NHEADS 2
#define NLAYERS 4
#define ECLS 5
#define NBUCK 196              // ceil(N / 512); bucket = dst >> 9
#define NBLK 256               // coarse pass blocks
#define EPB (N_EDGES / NBLK)   // 6250 edges per coarse block (exact)

// bf16 (stored as ushort) -> f32
__device__ inline float bf_lo(unsigned int u) { return __uint_as_float(u << 16); }
__device__ inline float bf_hi(unsigned int u) { return __uint_as_float(u & 0xffff0000u); }
// f32 -> bf16 bits, round-to-nearest-even
__device__ inline unsigned short f2bf(float f) {
    unsigned int u = __float_as_uint(f);
    u += 0x7FFFu + ((u >> 16) & 1u);
    return (unsigned short)(u >> 16);
}

// ---------------- CSR build: two-level bucket sort, no global atomics ------

__global__ void k_chist(const int* __restrict__ dst, int* __restrict__ bh) {
    __shared__ int lh[NBUCK];
    int tid = threadIdx.x, blk = blockIdx.x;
    for (int i = tid; i < NBUCK; i += 256) lh[i] = 0;
    __syncthreads();
    int s = blk * EPB, e = s + EPB;
    for (int i = s + tid; i < e; i += 256) atomicAdd(&lh[dst[i] >> 9], 1);
    __syncthreads();
    for (int i = tid; i < NBUCK; i += 256) bh[i * 256 + blk] = lh[i];
}

__global__ void k_s1(const int* __restrict__ bh, int* __restrict__ bbase,
                     int* __restrict__ part) {
    __shared__ int tmp[256];
    int tid = threadIdx.x;
    int i = blockIdx.x * 256 + tid;
    int v = bh[i];
    tmp[tid] = v;
    __syncthreads();
    for (int off = 1; off < 256; off <<= 1) {
        int t = (tid >= off) ? tmp[tid - off] : 0;
        __syncthreads();
        tmp[tid] += t;
        __syncthreads();
    }
    bbase[i] = tmp[tid] - v;
    if (tid == 255) part[blockIdx.x] = tmp[255];
}

// exclusive scan of bucket sums in-place; also computes escore (folded in).
__global__ void k_s2(int* __restrict__ part,
                     const float* __restrict__ eemb, const float* __restrict__ att_src,
                     float* __restrict__ escore) {
    __shared__ int tmp[256];
    int tid = threadIdx.x;
    int v = (tid < NBUCK) ? part[tid] : 0;
    tmp[tid] = v;
    __syncthreads();
    for (int off = 1; off < 256; off <<= 1) {
        int t = (tid >= off) ? tmp[tid - off] : 0;
        __syncthreads();
        tmp[tid] += t;
        __syncthreads();
    }
    if (tid < NBUCK) part[tid] = tmp[tid] - v;
    if (tid >= 200 && tid < 200 + NLAYERS * ECLS * NHEADS) {
        int idx = tid - 200;
        int l = idx / (ECLS * NHEADS);
        int r = idx % (ECLS * NHEADS);
        int c = r >> 1;
        int h = r & 1;
        float s = 0.f;
        const float* ev = eemb + l * ECLS * HC + c * HC + h * 32;
        const float* av = att_src + l * HC + h * 32;
        for (int k = 0; k < 32; ++k) s += ev[k] * av[k];
        escore[idx] = s;
    }
}

__global__ void k_cscatter(const int* __restrict__ src, const int* __restrict__ dst,
                           const int* __restrict__ attr, const int* __restrict__ bbase,
                           const int* __restrict__ part, int* __restrict__ bkt) {
    __shared__ int cur[NBUCK];
    int tid = threadIdx.x, blk = blockIdx.x;
    for (int i = tid; i < NBUCK; i += 256) cur[i] = bbase[i * 256 + blk] + part[i];
    __syncthreads();
    int s0 = blk * EPB, e0 = s0 + EPB;
    for (int i = s0 + tid; i < e0; i += 256) {
        int d = dst[i];
        int b = d >> 9;
        int pos = atomicAdd(&cur[b], 1);
        bkt[pos] = src[i] | (attr[i] << 17) | ((d & 511) << 20);
    }
}

__global__ void k_fine(const int* __restrict__ part, const int* __restrict__ bkt,
                       int* __restrict__ packed, int* __restrict__ rowstart) {
    __shared__ int hist[512];
    __shared__ int cur[512];
    int b = blockIdx.x, tid = threadIdx.x;   // 512 threads
    int base = part[b];
    int bend = (b + 1 < NBUCK) ? part[b + 1] : N_EDGES;
    int nb = bend - base;
    hist[tid] = 0;
    __syncthreads();
    for (int i = tid; i < nb; i += 512)
        atomicAdd(&hist[(bkt[base + i] >> 20) & 0x1FF], 1);
    __syncthreads();
    int v = hist[tid];
    for (int off = 1; off < 512; off <<= 1) {
        int t = (tid >= off) ? hist[tid - off] : 0;
        __syncthreads();
        hist[tid] += t;
        __syncthreads();
    }
    int excl = hist[tid] - v;
    int node = (b << 9) + tid;
    if (node <= N_NODES) rowstart[node] = base + excl;
    cur[tid] = excl;
    __syncthreads();
    for (int i = tid; i < nb; i += 512) {
        int p = bkt[base + i];
        int r = atomicAdd(&cur[(p >> 20) & 0x1FF], 1);
        packed[base + r] = p;
    }
}

// ---------------- layer-0 linear (Fin=4) ----------------
// One wave per node grid-stride; W column j in lane j's registers; row loads
// are wave-uniform so they scalarize.
__global__ void k_linear0(const float* __restrict__ in,
                          const float* __restrict__ W,        // [4][64]
                          const float* __restrict__ asrc, const float* __restrict__ adst,
                          unsigned short* __restrict__ hcurb,
                          float* __restrict__ ssrc, float* __restrict__ sdst) {
    int j = threadIdx.x & 63;
    int wid = (blockIdx.x * 256 + threadIdx.x) >> 6;
    int nwaves = gridDim.x * 4;

    float w0 = W[0 * HC + j], w1 = W[1 * HC + j], w2 = W[2 * HC + j], w3 = W[3 * HC + j];
    int head = j >> 5;
    int c = j & 31;
    float as = asrc[head * 32 + c];
    float ad = adst[head * 32 + c];

    for (int n = wid; n < N_NODES; n += nwaves) {
        int nu = __builtin_amdgcn_readfirstlane(n);
        float4 r = *(const float4*)(in + (size_t)nu * 4);
        float acc = r.x * w0 + r.y * w1 + r.z * w2 + r.w * w3;
        hcurb[(size_t)nu * HC + j] = f2bf(acc);
        float ps = acc * as;
        float pd = acc * ad;
        for (int off = 16; off > 0; off >>= 1) {
            ps += __shfl_down(ps, off, 32);
            pd += __shfl_down(pd, off, 32);
        }
        if (c == 0) {
            ssrc[nu * 2 + head] = ps;
            sdst[nu * 2 + head] = pd;
        }
    }
}

// ---------------- fused edge + next-layer linear (layers 0..2) ----------------
// Grid-stride, one wave per node. Edge loop: sub = lane>>3 (8 slots), q = lane&7
// (channels 8q..8q+7). Epilogue computes elu row in LDS, then immediately the
// NEXT layer's linear: hcurb_out = f2bf(o @ Wn) with Wn column j in registers
// (amortized over ~12 nodes/wave), plus next ssrc/sdst. hnext never hits HBM.
__global__ void k_edgelin(const int* __restrict__ rowstart, const int* __restrict__ packed,
                          const float* __restrict__ ssrc_in, const float* __restrict__ sdst_in,
                          const float* __restrict__ escore_l,    // [5][2]  layer l
                          const unsigned short* __restrict__ hcurb_in,
                          const float* __restrict__ eemb_l,      // [5][64] layer l
                          const float* __restrict__ bias_l,      // [64]    layer l
                          const float* __restrict__ Wn,          // [64][64] layer l+1
                          const float* __restrict__ asrc_n, const float* __restrict__ adst_n,
                          unsigned short* __restrict__ hcurb_out,
                          float* __restrict__ ssrc_out, float* __restrict__ sdst_out) {
    __shared__ float lbuf[4][64];
    int tid = threadIdx.x;
    int lane = tid & 63;
    int w = tid >> 6;
    int sub = lane >> 3;
    int q   = lane & 7;
    int h   = q >> 2;

    float wreg[64];
    #pragma unroll
    for (int k = 0; k < 64; ++k) wreg[k] = Wn[k * HC + lane];
    int head = lane >> 5;
    int c = lane & 31;
    float as = asrc_n[head * 32 + c];
    float ad = adst_n[head * 32 + c];

    int wid = (blockIdx.x * 256 + tid) >> 6;
    int nwaves = gridDim.x * 4;

    for (int n = wid; n < N_NODES; n += nwaves) {
        int beg = rowstart[n];
        int end = rowstart[n + 1];
        float sd = sdst_in[n * 2 + h];

        float4 a0 = make_float4(0.f, 0.f, 0.f, 0.f);
        float4 a1 = make_float4(0.f, 0.f, 0.f, 0.f);
        float ssum = 0.f;
        for (int i = beg + sub; i < end; i += 8) {
            int p = packed[i];
            int s = p & 0x1FFFF;
            int a = (p >> 17) & 7;
            float lg = sd + ssrc_in[s * 2 + h] + escore_l[a * 2 + h];
            lg = lg >= 0.f ? lg : 0.2f * lg;
            float wt = __expf(lg);
            uint4 hv = *(const uint4*)(hcurb_in + (size_t)s * HC + q * 8);
            const float4* ep = (const float4*)(eemb_l + a * HC + q * 8);
            float4 e0 = ep[0], e1 = ep[1];
            a0.x += wt * (bf_lo(hv.x) + e0.x);
            a0.y += wt * (bf_hi(hv.x) + e0.y);
            a0.z += wt * (bf_lo(hv.y) + e0.z);
            a0.w += wt * (bf_hi(hv.y) + e0.w);
            a1.x += wt * (bf_lo(hv.z) + e1.x);
            a1.y += wt * (bf_hi(hv.z) + e1.y);
            a1.z += wt * (bf_lo(hv.w) + e1.z);
            a1.w += wt * (bf_hi(hv.w) + e1.w);
            ssum += wt;
        }
        for (int off = 8; off < 64; off <<= 1) {
            a0.x += __shfl_xor(a0.x, off, 64);
            a0.y += __shfl_xor(a0.y, off, 64);
            a0.z += __shfl_xor(a0.z, off, 64);
            a0.w += __shfl_xor(a0.w, off, 64);
            a1.x += __shfl_xor(a1.x, off, 64);
            a1.y += __shfl_xor(a1.y, off, 64);
            a1.z += __shfl_xor(a1.z, off, 64);
            a1.w += __shfl_xor(a1.w, off, 64);
            ssum  += __shfl_xor(ssum,  off, 64);
        }
        if (sub == 0) {
            ((float4*)&lbuf[w][q * 8])[0] = a0;
            ((float4*)&lbuf[w][q * 8])[1] = a1;
        }
        float ssum_h = __shfl(ssum, (lane >> 5) * 4, 64);
        float inv = 1.f / (ssum_h + 1e-16f);
        __builtin_amdgcn_wave_barrier();
        float v = lbuf[w][lane] * inv + bias_l[lane];
        float o = v > 0.f ? v : (__expf(v) - 1.f);
        __builtin_amdgcn_wave_barrier();
        lbuf[w][lane] = o;                       // activated row, channel `lane`
        __builtin_amdgcn_wave_barrier();
        // next-layer linear: acc = sum_k o[k] * Wn[k][lane]
        const float4* rp = (const float4*)&lbuf[w][0];
        float acc = 0.f;
        #pragma unroll
        for (int k4 = 0; k4 < 16; ++k4) {
            float4 r = rp[k4];                   // broadcast ds_read_b128
            acc += r.x * wreg[k4 * 4 + 0];
            acc += r.y * wreg[k4 * 4 + 1];
            acc += r.z * wreg[k4 * 4 + 2];
            acc += r.w * wreg[k4 * 4 + 3];
        }
        hcurb_out[(size_t)n * HC + lane] = f2bf(acc);
        float ps = acc * as;
        float pd = acc * ad;
        for (int off = 16; off > 0; off >>= 1) {
            ps += __shfl_down(ps, off, 32);
            pd += __shfl_down(pd, off, 32);
        }
        if (c == 0) {
            ssrc_out[n * 2 + head] = ps;
            sdst_out[n * 2 + head] = pd;
        }
        __builtin_amdgcn_wave_barrier();         // before next node reuses lbuf
    }
}

// ---------------- last edge layer + fused MF decoder ----------------
// Block = 4 nodes (4b..4b+3); out[b] = dot(h[4b], h[4b+1]).
__global__ void k_edge_last(const int* __restrict__ rowstart, const int* __restrict__ packed,
                            const float* __restrict__ ssrc, const float* __restrict__ sdst,
                            const float* __restrict__ escore_l,
                            const unsigned short* __restrict__ hcurb,
                            const float* __restrict__ eemb_l,
                            const float* __restrict__ bias_l,
                            float* __restrict__ out) {
    __shared__ float lbuf[4][64];
    __shared__ float obuf[2][64];
    int w = threadIdx.x >> 6;
    int n = blockIdx.x * 4 + w;
    int lane = threadIdx.x & 63;
    int sub = lane >> 3;
    int q   = lane & 7;
    int h   = q >> 2;

    int beg = rowstart[n];
    int end = rowstart[n + 1];
    float sd = sdst[n * 2 + h];

    float4 a0 = make_float4(0.f, 0.f, 0.f, 0.f);
    float4 a1 = make_float4(0.f, 0.f, 0.f, 0.f);
    float ssum = 0.f;
    for (int i = beg + sub; i < end; i += 8) {
        int p = packed[i];
        int s = p & 0x1FFFF;
        int a = (p >> 17) & 7;
        float lg = sd + ssrc[s * 2 + h] + escore_l[a * 2 + h];
        lg = lg >= 0.f ? lg : 0.2f * lg;
        float wt = __expf(lg);
        uint4 hv = *(const uint4*)(hcurb + (size_t)s * HC + q * 8);
        const float4* ep = (const float4*)(eemb_l + a * HC + q * 8);
        float4 e0 = ep[0], e1 = ep[1];
        a0.x += wt * (bf_lo(hv.x) + e0.x);
        a0.y += wt * (bf_hi(hv.x) + e0.y);
        a0.z += wt * (bf_lo(hv.y) + e0.z);
        a0.w += wt * (bf_hi(hv.y) + e0.w);
        a1.x += wt * (bf_lo(hv.z) + e1.x);
        a1.y += wt * (bf_hi(hv.z) + e1.y);
        a1.z += wt * (bf_lo(hv.w) + e1.z);
        a1.w += wt * (bf_hi(hv.w) + e1.w);
        ssum += wt;
    }
    for (int off = 8; off < 64; off <<= 1) {
        a0.x += __shfl_xor(a0.x, off, 64);
        a0.y += __shfl_xor(a0.y, off, 64);
        a0.z += __shfl_xor(a0.z, off, 64);
        a0.w += __shfl_xor(a0.w, off, 64);
        a1.x += __shfl_xor(a1.x, off, 64);
        a1.y += __shfl_xor(a1.y, off, 64);
        a1.z += __shfl_xor(a1.z, off, 64);
        a1.w += __shfl_xor(a1.w, off, 64);
        ssum  += __shfl_xor(ssum,  off, 64);
    }
    if (sub == 0) {
        ((float4*)&lbuf[w][q * 8])[0] = a0;
        ((float4*)&lbuf[w][q * 8])[1] = a1;
    }
    float ssum_h = __shfl(ssum, (lane >> 5) * 4, 64);
    float inv = 1.f / (ssum_h + 1e-16f);
    __builtin_amdgcn_wave_barrier();
    float v = lbuf[w][lane] * inv + bias_l[lane];
    float o = v > 0.f ? v : (__expf(v) - 1.f);
    if (w < 2) obuf[w][lane] = o;               // nodes 4b (user), 4b+1 (item)
    __syncthreads();
    if (w == 0) {
        float p = obuf[0][lane] * obuf[1][lane];
        for (int off = 32; off > 0; off >>= 1) p += __shfl_down(p, off, 64);
        if (lane == 0) out[blockIdx.x] = p;
    }
}

// ---------------- launch ----------------
extern "C" void kernel_launch(void* const* d_in, const int* in_sizes, int n_in,
                              void* d_out, int out_size, void* d_ws, size_t ws_size,
                              hipStream_t stream) {
    const float* x       = (const float*)d_in[0];   // [N,4]
    const float* W0      = (const float*)d_in[1];   // [4,64]
    const float* W13     = (const float*)d_in[2];   // [3,64,64]
    const float* eemb    = (const float*)d_in[3];   // [4,5,64]
    const float* att_src = (const float*)d_in[4];   // [4,2,32]
    const float* att_dst = (const float*)d_in[5];   // [4,2,32]
    const float* bias    = (const float*)d_in[6];   // [4,64]
    const int*   eidx    = (const int*)d_in[7];     // [2,E]
    const int*   eattr   = (const int*)d_in[8];     // [E]
    float* out = (float*)d_out;

    const int* src = eidx;
    const int* dst = eidx + N_EDGES;

    // workspace layout (double-buffered node state)
    char* wsb = (char*)d_ws;
    size_t off = 0;
    auto alloc = [&](size_t bytes) { char* p = wsb + off; off += (bytes + 255) & ~(size_t)255; return p; };
    unsigned short* hA     = (unsigned short*)alloc((size_t)N_NODES * HC * 2);
    unsigned short* hB     = (unsigned short*)alloc((size_t)N_NODES * HC * 2);
    float*          ssrcA  = (float*)alloc((size_t)N_NODES * 2 * 4);
    float*          ssrcB  = (float*)alloc((size_t)N_NODES * 2 * 4);
    float*          sdstA  = (float*)alloc((size_t)N_NODES * 2 * 4);
    float*          sdstB  = (float*)alloc((size_t)N_NODES * 2 * 4);
    float*          escore = (float*)alloc(NLAYERS * ECLS * NHEADS * 4);
    int*            bh     = (int*)alloc((size_t)NBUCK * 256 * 4);
    int*            bbase  = (int*)alloc((size_t)NBUCK * 256 * 4);
    int*            part   = (int*)alloc(256 * 4);
    int*            rowstart = (int*)alloc(((size_t)N_NODES + 1) * 4);
    int*            bkt    = (int*)alloc((size_t)N_EDGES * 4);
    int*            packed = (int*)alloc((size_t)N_EDGES * 4);

    // ---- CSR build: bucket sort, no global atomics ----
    k_chist<<<NBLK, 256, 0, stream>>>(dst, bh);
    k_s1<<<NBUCK, 256, 0, stream>>>(bh, bbase, part);
    k_s2<<<1, 256, 0, stream>>>(part, eemb, att_src, escore);
    k_cscatter<<<NBLK, 256, 0, stream>>>(src, dst, eattr, bbase, part, bkt);
    k_fine<<<NBUCK, 512, 0, stream>>>(part, bkt, packed, rowstart);

    // layer-0 linear: x -> hA, ssrcA, sdstA (att layer 0)
    k_linear0<<<1024, 256, 0, stream>>>(x, W0, att_src, att_dst, hA, ssrcA, sdstA);

    // layers 0..2: fused edge(l) + linear(l+1). Ping-pong A<->B.
    unsigned short* hin = hA;  unsigned short* hout = hB;
    float *sin_ = ssrcA, *sout = ssrcB, *din = sdstA, *dout_ = sdstB;
    for (int l = 0; l < NLAYERS - 1; ++l) {
        k_edgelin<<<2048, 256, 0, stream>>>(
            rowstart, packed, sin_, din, escore + l * ECLS * NHEADS, hin,
            eemb + (size_t)l * ECLS * HC, bias + l * HC,
            W13 + (size_t)l * HC * HC, att_src + (l + 1) * HC, att_dst + (l + 1) * HC,
            hout, sout, dout_);
        unsigned short* ht = hin; hin = hout; hout = ht;
        float* t;
        t = sin_; sin_ = sout; sout = t;
        t = din;  din  = dout_; dout_ = t;
    }

    // layer 3: edge + fused MF decoder
    k_edge_last<<<N_NODES / 4, 256, 0, stream>>>(
        rowstart, packed, sin_, din, escore + 3 * ECLS * NHEADS, hin,
        eemb + (size_t)3 * ECLS * HC, bias + 3 * HC, out);
}

// Round 12
// 382.419 us; speedup vs baseline: 1.1837x; 1.1837x over previous
//
#include <hip/hip_runtime.h>
#include <hip/hip_bf16.h>
#include <math.h>

#define N_NODES 100000
#define N_EDGES 1600000
#define HC 64          // H*C
#define NHEADS 2
#define NLAYERS 4
#define ECLS 5
#define NBUCK 196              // ceil(N / 512); bucket = dst >> 9
#define NBLK 256               // coarse pass blocks
#define EPB (N_EDGES / NBLK)   // 6250 edges per coarse block (exact)
#define NGRP (N_NODES / 16)    // 6250 16-node groups (exact)

typedef __attribute__((ext_vector_type(8))) short short8;
typedef __attribute__((ext_vector_type(4))) float floatx4;
union F8 { uint4 u; short8 s; };

// bf16 (stored as ushort) -> f32
__device__ inline float bf_lo(unsigned int u) { return __uint_as_float(u << 16); }
__device__ inline float bf_hi(unsigned int u) { return __uint_as_float(u & 0xffff0000u); }
// f32 -> bf16 bits, round-to-nearest-even
__device__ inline unsigned short f2bf(float f) {
    unsigned int u = __float_as_uint(f);
    u += 0x7FFFu + ((u >> 16) & 1u);
    return (unsigned short)(u >> 16);
}

// ---------------- CSR build: two-level bucket sort, no global atomics ------

__global__ void k_chist(const int* __restrict__ dst, int* __restrict__ bh) {
    __shared__ int lh[NBUCK];
    int tid = threadIdx.x, blk = blockIdx.x;
    for (int i = tid; i < NBUCK; i += 256) lh[i] = 0;
    __syncthreads();
    int s = blk * EPB, e = s + EPB;
    for (int i = s + tid; i < e; i += 256) atomicAdd(&lh[dst[i] >> 9], 1);
    __syncthreads();
    for (int i = tid; i < NBUCK; i += 256) bh[i * 256 + blk] = lh[i];
}

__global__ void k_s1(const int* __restrict__ bh, int* __restrict__ bbase,
                     int* __restrict__ part) {
    __shared__ int tmp[256];
    int tid = threadIdx.x;
    int i = blockIdx.x * 256 + tid;
    int v = bh[i];
    tmp[tid] = v;
    __syncthreads();
    for (int off = 1; off < 256; off <<= 1) {
        int t = (tid >= off) ? tmp[tid - off] : 0;
        __syncthreads();
        tmp[tid] += t;
        __syncthreads();
    }
    bbase[i] = tmp[tid] - v;
    if (tid == 255) part[blockIdx.x] = tmp[255];
}

// exclusive scan of bucket sums in-place; also computes escore (folded in).
__global__ void k_s2(int* __restrict__ part,
                     const float* __restrict__ eemb, const float* __restrict__ att_src,
                     float* __restrict__ escore) {
    __shared__ int tmp[256];
    int tid = threadIdx.x;
    int v = (tid < NBUCK) ? part[tid] : 0;
    tmp[tid] = v;
    __syncthreads();
    for (int off = 1; off < 256; off <<= 1) {
        int t = (tid >= off) ? tmp[tid - off] : 0;
        __syncthreads();
        tmp[tid] += t;
        __syncthreads();
    }
    if (tid < NBUCK) part[tid] = tmp[tid] - v;
    if (tid >= 200 && tid < 200 + NLAYERS * ECLS * NHEADS) {
        int idx = tid - 200;
        int l = idx / (ECLS * NHEADS);
        int r = idx % (ECLS * NHEADS);
        int c = r >> 1;
        int h = r & 1;
        float s = 0.f;
        const float* ev = eemb + l * ECLS * HC + c * HC + h * 32;
        const float* av = att_src + l * HC + h * 32;
        for (int k = 0; k < 32; ++k) s += ev[k] * av[k];
        escore[idx] = s;
    }
}

__global__ void k_cscatter(const int* __restrict__ src, const int* __restrict__ dst,
                           const int* __restrict__ attr, const int* __restrict__ bbase,
                           const int* __restrict__ part, int* __restrict__ bkt) {
    __shared__ int cur[NBUCK];
    int tid = threadIdx.x, blk = blockIdx.x;
    for (int i = tid; i < NBUCK; i += 256) cur[i] = bbase[i * 256 + blk] + part[i];
    __syncthreads();
    int s0 = blk * EPB, e0 = s0 + EPB;
    for (int i = s0 + tid; i < e0; i += 256) {
        int d = dst[i];
        int b = d >> 9;
        int pos = atomicAdd(&cur[b], 1);
        bkt[pos] = src[i] | (attr[i] << 17) | ((d & 511) << 20);
    }
}

__global__ void k_fine(const int* __restrict__ part, const int* __restrict__ bkt,
                       int* __restrict__ packed, int* __restrict__ rowstart) {
    __shared__ int hist[512];
    __shared__ int cur[512];
    int b = blockIdx.x, tid = threadIdx.x;   // 512 threads
    int base = part[b];
    int bend = (b + 1 < NBUCK) ? part[b + 1] : N_EDGES;
    int nb = bend - base;
    hist[tid] = 0;
    __syncthreads();
    for (int i = tid; i < nb; i += 512)
        atomicAdd(&hist[(bkt[base + i] >> 20) & 0x1FF], 1);
    __syncthreads();
    int v = hist[tid];
    for (int off = 1; off < 512; off <<= 1) {
        int t = (tid >= off) ? hist[tid - off] : 0;
        __syncthreads();
        hist[tid] += t;
        __syncthreads();
    }
    int excl = hist[tid] - v;
    int node = (b << 9) + tid;
    if (node <= N_NODES) rowstart[node] = base + excl;
    cur[tid] = excl;
    __syncthreads();
    for (int i = tid; i < nb; i += 512) {
        int p = bkt[base + i];
        int r = atomicAdd(&cur[(p >> 20) & 0x1FF], 1);
        packed[base + r] = p;
    }
}

// ---------------- layer-0 linear (Fin=4) ----------------
__global__ void k_linear0(const float* __restrict__ in,
                          const float* __restrict__ W,        // [4][64]
                          const float* __restrict__ asrc, const float* __restrict__ adst,
                          unsigned short* __restrict__ hcurb,
                          float* __restrict__ ssrc, float* __restrict__ sdst) {
    int j = threadIdx.x & 63;
    int wid = (blockIdx.x * 256 + threadIdx.x) >> 6;
    int nwaves = gridDim.x * 4;

    float w0 = W[0 * HC + j], w1 = W[1 * HC + j], w2 = W[2 * HC + j], w3 = W[3 * HC + j];
    int head = j >> 5;
    int c = j & 31;
    float as = asrc[head * 32 + c];
    float ad = adst[head * 32 + c];

    for (int n = wid; n < N_NODES; n += nwaves) {
        int nu = __builtin_amdgcn_readfirstlane(n);
        float4 r = *(const float4*)(in + (size_t)nu * 4);
        float acc = r.x * w0 + r.y * w1 + r.z * w2 + r.w * w3;
        hcurb[(size_t)nu * HC + j] = f2bf(acc);
        float ps = acc * as;
        float pd = acc * ad;
        for (int off = 16; off > 0; off >>= 1) {
            ps += __shfl_down(ps, off, 32);
            pd += __shfl_down(pd, off, 32);
        }
        if (c == 0) {
            ssrc[nu * 2 + head] = ps;
            sdst[nu * 2 + head] = pd;
        }
    }
}

// ---------------- MFMA linear (layers 1..3) ----------------
// hcurb[N,64] = actB[N,64](bf16) @ W[64,64], plus ssrc/sdst.
// One wave per 16-node group (grid-stride). 8 x mfma_f32_16x16x32_bf16.
// A frag: A[m=lane&15][k=(lane>>4)*8+j] -> one dwordx4/lane per 32-K chunk.
// B (=W) frags: block stages fragment-ordered bf16 into LDS once, each wave
// keeps all 8 frags (32 VGPRs). C: col=lane&15 (channel in tile),
// row=(lane>>4)*4+reg (node). hcurb written via LDS bounce -> coalesced.
__global__ void k_linmfma(const unsigned short* __restrict__ actB,
                          const float* __restrict__ Wl,       // [64][64] fp32
                          const float* __restrict__ asrc,     // [64]
                          const float* __restrict__ adst,     // [64]
                          unsigned short* __restrict__ hcurb,
                          float* __restrict__ ssrc, float* __restrict__ sdst) {
    __shared__ uint4 WB[512];            // 8 frag-sets x 64 lanes x 16 B = 8 KB
    __shared__ unsigned short Cb[4][1024];  // per-wave 16x64 bf16 bounce, 8 KB
    int tid = threadIdx.x;
    int lane = tid & 63;
    int w = tid >> 6;
    int q = lane >> 4;
    int c = lane & 15;

    // stage W fragments: rid = (kk*4 + t)*64 + ln
    for (int rid = tid; rid < 512; rid += 256) {
        int kk = rid >> 8;
        int t  = (rid >> 6) & 3;
        int ln = rid & 63;
        int qq = ln >> 4, cc = ln & 15;
        unsigned int u[4];
        #pragma unroll
        for (int jj = 0; jj < 4; ++jj) {
            float v0 = Wl[(kk * 32 + qq * 8 + jj * 2 + 0) * 64 + 16 * t + cc];
            float v1 = Wl[(kk * 32 + qq * 8 + jj * 2 + 1) * 64 + 16 * t + cc];
            u[jj] = (unsigned int)f2bf(v0) | ((unsigned int)f2bf(v1) << 16);
        }
        WB[rid] = make_uint4(u[0], u[1], u[2], u[3]);
    }
    __syncthreads();

    short8 bfr[2][4];
    #pragma unroll
    for (int kk = 0; kk < 2; ++kk)
        #pragma unroll
        for (int t = 0; t < 4; ++t) {
            F8 tmp; tmp.u = WB[(kk * 4 + t) * 64 + lane];
            bfr[kk][t] = tmp.s;
        }

    float as_[4], ad_[4];
    #pragma unroll
    for (int t = 0; t < 4; ++t) {
        as_[t] = asrc[16 * t + c];
        ad_[t] = adst[16 * t + c];
    }

    int wid = (blockIdx.x * 256 + tid) >> 6;
    int nwaves = gridDim.x * 4;

    for (int g = wid; g < NGRP; g += nwaves) {
        int base = g * 16;
        F8 a0, a1;
        a0.u = *(const uint4*)(actB + (size_t)(base + c) * HC + q * 8);
        a1.u = *(const uint4*)(actB + (size_t)(base + c) * HC + 32 + q * 8);

        floatx4 acc[4];
        #pragma unroll
        for (int t = 0; t < 4; ++t) {
            acc[t] = (floatx4){0.f, 0.f, 0.f, 0.f};
            acc[t] = __builtin_amdgcn_mfma_f32_16x16x32_bf16(a0.s, bfr[0][t], acc[t], 0, 0, 0);
            acc[t] = __builtin_amdgcn_mfma_f32_16x16x32_bf16(a1.s, bfr[1][t], acc[t], 0, 0, 0);
        }

        // ssrc/sdst: per reg r, node = base + q*4 + r; reduce over c (16 lanes)
        #pragma unroll
        for (int r = 0; r < 4; ++r) {
            float h0s = acc[0][r] * as_[0] + acc[1][r] * as_[1];
            float h1s = acc[2][r] * as_[2] + acc[3][r] * as_[3];
            float h0d = acc[0][r] * ad_[0] + acc[1][r] * ad_[1];
            float h1d = acc[2][r] * ad_[2] + acc[3][r] * ad_[3];
            #pragma unroll
            for (int off = 1; off < 16; off <<= 1) {
                h0s += __shfl_xor(h0s, off, 64);
                h1s += __shfl_xor(h1s, off, 64);
                h0d += __shfl_xor(h0d, off, 64);
                h1d += __shfl_xor(h1d, off, 64);
            }
            if (c == 0) {
                int node = base + q * 4 + r;
                *(float2*)(ssrc + node * 2) = make_float2(h0s, h1s);
                *(float2*)(sdst + node * 2) = make_float2(h0d, h1d);
            }
        }

        // hcurb: bounce C through LDS, then coalesced dwordx4 stores
        #pragma unroll
        for (int t = 0; t < 4; ++t)
            #pragma unroll
            for (int r = 0; r < 4; ++r)
                Cb[w][(q * 4 + r) * 64 + 16 * t + c] = f2bf(acc[t][r]);
        __builtin_amdgcn_wave_barrier();
        const uint4* cf = (const uint4*)&Cb[w][0];
        uint4* gout = (uint4*)(hcurb + (size_t)base * HC);
        gout[lane] = cf[lane];
        gout[64 + lane] = cf[64 + lane];
        __builtin_amdgcn_wave_barrier();
    }
}

// ---------------- fused edge pipeline ----------------
// One wave per dst node; block = 4 nodes. sub = lane>>3 (8 edge slots),
// q = lane&7 (channels 8q..8q+7). Output stored bf16 (actnext) for MFMA.
// LAST: fuse MF decoder — out[b] = dot(h[4b], h[4b+1]).
template <bool LAST>
__global__ void k_edge(const int* __restrict__ rowstart, const int* __restrict__ packed,
                       const float* __restrict__ ssrc, const float* __restrict__ sdst,
                       const float* __restrict__ escore_l,   // [5][2]
                       const unsigned short* __restrict__ hcurb, // [N][64] bf16
                       const float* __restrict__ eemb_l,     // [5][64]
                       const float* __restrict__ bias_l,     // [64]
                       unsigned short* __restrict__ actnext, float* __restrict__ out) {
    __shared__ float lbuf[4][64];
    __shared__ float obuf[2][64];
    int w = threadIdx.x >> 6;
    int n = blockIdx.x * 4 + w;
    int lane = threadIdx.x & 63;
    int sub = lane >> 3;
    int q   = lane & 7;
    int h   = q >> 2;

    int beg = rowstart[n];
    int end = rowstart[n + 1];
    float sd = sdst[n * 2 + h];

    float4 a0 = make_float4(0.f, 0.f, 0.f, 0.f);
    float4 a1 = make_float4(0.f, 0.f, 0.f, 0.f);
    float ssum = 0.f;
    for (int i = beg + sub; i < end; i += 8) {
        int p = packed[i];
        int s = p & 0x1FFFF;
        int a = (p >> 17) & 7;
        float lg = sd + ssrc[s * 2 + h] + escore_l[a * 2 + h];
        lg = lg >= 0.f ? lg : 0.2f * lg;
        float wt = __expf(lg);
        uint4 hv = *(const uint4*)(hcurb + (size_t)s * HC + q * 8);
        const float4* ep = (const float4*)(eemb_l + a * HC + q * 8);
        float4 e0 = ep[0], e1 = ep[1];
        a0.x += wt * (bf_lo(hv.x) + e0.x);
        a0.y += wt * (bf_hi(hv.x) + e0.y);
        a0.z += wt * (bf_lo(hv.y) + e0.z);
        a0.w += wt * (bf_hi(hv.y) + e0.w);
        a1.x += wt * (bf_lo(hv.z) + e1.x);
        a1.y += wt * (bf_hi(hv.z) + e1.y);
        a1.z += wt * (bf_lo(hv.w) + e1.z);
        a1.w += wt * (bf_hi(hv.w) + e1.w);
        ssum += wt;
    }
    for (int off = 8; off < 64; off <<= 1) {
        a0.x += __shfl_xor(a0.x, off, 64);
        a0.y += __shfl_xor(a0.y, off, 64);
        a0.z += __shfl_xor(a0.z, off, 64);
        a0.w += __shfl_xor(a0.w, off, 64);
        a1.x += __shfl_xor(a1.x, off, 64);
        a1.y += __shfl_xor(a1.y, off, 64);
        a1.z += __shfl_xor(a1.z, off, 64);
        a1.w += __shfl_xor(a1.w, off, 64);
        ssum  += __shfl_xor(ssum,  off, 64);
    }
    if (sub == 0) {
        ((float4*)&lbuf[w][q * 8])[0] = a0;
        ((float4*)&lbuf[w][q * 8])[1] = a1;
    }
    // ssum for head of CHANNEL `lane` (= lane>>5): lane 0 holds head0, lane 4 head1
    float ssum_h = __shfl(ssum, (lane >> 5) * 4, 64);
    float inv = 1.f / (ssum_h + 1e-16f);
    __builtin_amdgcn_wave_barrier();
    float v = lbuf[w][lane] * inv + bias_l[lane];
    float o = v > 0.f ? v : (__expf(v) - 1.f);
    if (!LAST) {
        actnext[(size_t)n * HC + lane] = f2bf(o);
    } else {
        if (w < 2) obuf[w][lane] = o;           // nodes 4b (user), 4b+1 (item)
        __syncthreads();
        if (w == 0) {
            float p = obuf[0][lane] * obuf[1][lane];
            for (int off = 32; off > 0; off >>= 1) p += __shfl_down(p, off, 64);
            if (lane == 0) out[blockIdx.x] = p;
        }
    }
}

// ---------------- launch ----------------
extern "C" void kernel_launch(void* const* d_in, const int* in_sizes, int n_in,
                              void* d_out, int out_size, void* d_ws, size_t ws_size,
                              hipStream_t stream) {
    const float* x       = (const float*)d_in[0];   // [N,4]
    const float* W0      = (const float*)d_in[1];   // [4,64]
    const float* W13     = (const float*)d_in[2];   // [3,64,64]
    const float* eemb    = (const float*)d_in[3];   // [4,5,64]
    const float* att_src = (const float*)d_in[4];   // [4,2,32]
    const float* att_dst = (const float*)d_in[5];   // [4,2,32]
    const float* bias    = (const float*)d_in[6];   // [4,64]
    const int*   eidx    = (const int*)d_in[7];     // [2,E]
    const int*   eattr   = (const int*)d_in[8];     // [E]
    float* out = (float*)d_out;

    const int* src = eidx;
    const int* dst = eidx + N_EDGES;

    char* wsb = (char*)d_ws;
    size_t off = 0;
    auto alloc = [&](size_t bytes) { char* p = wsb + off; off += (bytes + 255) & ~(size_t)255; return p; };
    unsigned short* hcurb  = (unsigned short*)alloc((size_t)N_NODES * HC * 2);
    unsigned short* actB   = (unsigned short*)alloc((size_t)N_NODES * HC * 2);
    float*          ssrc   = (float*)alloc((size_t)N_NODES * 2 * 4);
    float*          sdst   = (float*)alloc((size_t)N_NODES * 2 * 4);
    float*          escore = (float*)alloc(NLAYERS * ECLS * NHEADS * 4);
    int*            bh     = (int*)alloc((size_t)NBUCK * 256 * 4);
    int*            bbase  = (int*)alloc((size_t)NBUCK * 256 * 4);
    int*            part   = (int*)alloc(256 * 4);
    int*            rowstart = (int*)alloc(((size_t)N_NODES + 1) * 4);
    int*            bkt    = (int*)alloc((size_t)N_EDGES * 4);
    int*            packed = (int*)alloc((size_t)N_EDGES * 4);

    // ---- CSR build ----
    k_chist<<<NBLK, 256, 0, stream>>>(dst, bh);
    k_s1<<<NBUCK, 256, 0, stream>>>(bh, bbase, part);
    k_s2<<<1, 256, 0, stream>>>(part, eemb, att_src, escore);
    k_cscatter<<<NBLK, 256, 0, stream>>>(src, dst, eattr, bbase, part, bkt);
    k_fine<<<NBUCK, 512, 0, stream>>>(part, bkt, packed, rowstart);

    // layer 0 linear
    k_linear0<<<1024, 256, 0, stream>>>(x, W0, att_src, att_dst, hcurb, ssrc, sdst);

    for (int l = 0; l < NLAYERS; ++l) {
        if (l > 0) {
            k_linmfma<<<512, 256, 0, stream>>>(
                actB, W13 + (size_t)(l - 1) * HC * HC,
                att_src + l * HC, att_dst + l * HC, hcurb, ssrc, sdst);
        }
        const float* esl = escore + l * ECLS * NHEADS;
        const float* el  = eemb + (size_t)l * ECLS * HC;
        const float* bl  = bias + l * HC;
        if (l < NLAYERS - 1)
            k_edge<false><<<N_NODES / 4, 256, 0, stream>>>(
                rowstart, packed, ssrc, sdst, esl, hcurb, el, bl, actB, nullptr);
        else
            k_edge<true><<<N_NODES / 4, 256, 0, stream>>>(
                rowstart, packed, ssrc, sdst, esl, hcurb, el, bl, nullptr, out);
    }
}